// Round 4
// baseline (550.896 us; speedup 1.0000x reference)
//
#include <hip/hip_runtime.h>
#include <hip/hip_bf16.h>
#include <stdint.h>

typedef __attribute__((ext_vector_type(8))) __bf16 bf16x8;
typedef __attribute__((ext_vector_type(4))) float f32x4;

static __device__ __forceinline__ unsigned short f2bf(float f) {
    unsigned int u = __float_as_uint(f);
    unsigned int r = (u + 0x7fffu + ((u >> 16) & 1u)) >> 16;
    return (unsigned short)r;
}

// ---------------- Kernel 1: weight fp32 -> bf16 ----------------
__global__ __launch_bounds__(256) void wconv_kernel(
    const float* __restrict__ w, unsigned short* __restrict__ wb)
{
    const int i = blockIdx.x * 256 + threadIdx.x;
    const float4 v = ((const float4*)w)[i];
    ushort4 o;
    o.x = f2bf(v.x); o.y = f2bf(v.y); o.z = f2bf(v.z); o.w = f2bf(v.w);
    ((ushort4*)wb)[i] = o;
}

// ---------------- Kernel 2: fused prune + variance-scale + 256x256x64 GEMM ----------------
// Register-budget-aware rework of round 3: single bk set (B re-read per phase),
// in-place prune (no p regs), split A-prefetch halves. Target < 128 arch VGPRs.
#define KD 1024
#define ND 1024

#define GLL16(gp, lp)                                                          \
    __builtin_amdgcn_global_load_lds(                                          \
        (const __attribute__((address_space(1))) void*)(gp),                   \
        (__attribute__((address_space(3))) void*)(lp), 16, 0, 0)

#define VMW(n) asm volatile("s_waitcnt vmcnt(" #n ")" ::: "memory")

#define BSTAGE(BUFB, kh, ktoff) {                                              \
    const unsigned short* _s = bG + (ktoff) + (kh) * 32;                       \
    char* _dp = smem + 65536 + (BUFB) + (kh) * 16384 + w * 1024;               \
    GLL16(_s, _dp); GLL16(_s + 128 * KD, _dp + 8192); }

#define LOADA(BUFB, mh, ks) {                                                  \
    const char* _ab = smem + (BUFB) + (ks) * 16384 + aR0 + (mh) * 4096;        \
    af[0] = *(const bf16x8*)(_ab);                                             \
    af[1] = *(const bf16x8*)(_ab + 1024);                                      \
    af[2] = *(const bf16x8*)(_ab + 2048);                                      \
    af[3] = *(const bf16x8*)(_ab + 3072); }

#define LOADB(BUFB, ks) {                                                      \
    const char* _bb = smem + 65536 + (BUFB) + (ks) * 16384 + bR0;              \
    bk[0] = *(const bf16x8*)(_bb);                                             \
    bk[1] = *(const bf16x8*)(_bb + 1024);                                      \
    bk[2] = *(const bf16x8*)(_bb + 2048);                                      \
    bk[3] = *(const bf16x8*)(_bb + 3072); }

#define AXH0(ktoff) {                                                          \
    ax0 = *(const float4*)(xT + (ktoff));                                      \
    ax1 = *(const float4*)(xT + (ktoff) + 4);                                  \
    ax2 = *(const float4*)(xT + (ktoff) + 8);                                  \
    ax3 = *(const float4*)(xT + (ktoff) + 12); }

#define AXH1(ktoff) {                                                          \
    ax4 = *(const float4*)(xT + (ktoff) + 32);                                 \
    ax5 = *(const float4*)(xT + (ktoff) + 36);                                 \
    ax6 = *(const float4*)(xT + (ktoff) + 40);                                 \
    ax7 = *(const float4*)(xT + (ktoff) + 44); }

#define PRUNE_IP(g) {                                                          \
    const float b0 = fabsf(g.x), b1 = fabsf(g.y), b2 = fabsf(g.z), b3 = fabsf(g.w); \
    const int r0 = (b1 >  b0) + (b2 >  b0) + (b3 >  b0);                       \
    const int r1 = (b0 >= b1) + (b2 >  b1) + (b3 >  b1);                       \
    const int r2 = (b0 >= b2) + (b1 >= b2) + (b3 >  b2);                       \
    const int r3 = (b0 >= b3) + (b1 >= b3) + (b2 >= b3);                       \
    g.x = (r0 < 2) ? g.x : 0.0f;                                               \
    g.y = (r1 < 2) ? g.y : 0.0f;                                               \
    g.z = (r2 < 2) ? g.z : 0.0f;                                               \
    g.w = (r3 < 2) ? g.w : 0.0f; }

#define SUMS2(sa, sb, a, b, c, d) {                                            \
    sa += ((a.x + a.y) + (a.z + a.w)) + ((b.x + b.y) + (b.z + b.w))            \
        + ((c.x + c.y) + (c.z + c.w)) + ((d.x + d.y) + (d.z + d.w));           \
    sb += (a.x*a.x + a.y*a.y + a.z*a.z + a.w*a.w)                              \
        + (b.x*b.x + b.y*b.y + b.z*b.z + b.w*b.w)                              \
        + (c.x*c.x + c.y*c.y + c.z*c.z + c.w*c.w)                              \
        + (d.x*d.x + d.y*d.y + d.z*d.z + d.w*d.w); }

#define PACK8(pa, pb, dstb) {                                                  \
    union { ushort h[8]; uint4 q; } _k;                                        \
    _k.h[0] = f2bf(pa.x); _k.h[1] = f2bf(pa.y);                                \
    _k.h[2] = f2bf(pa.z); _k.h[3] = f2bf(pa.w);                                \
    _k.h[4] = f2bf(pb.x); _k.h[5] = f2bf(pb.y);                                \
    _k.h[6] = f2bf(pb.z); _k.h[7] = f2bf(pb.w);                                \
    *(uint4*)(dstb) = _k.q; }

#define PW_H0(DSTB, DOACC) {                                                   \
    if (DOACC) { SUMS2(sx, sxx, ax0, ax1, ax2, ax3); }                         \
    PRUNE_IP(ax0); PRUNE_IP(ax1); PRUNE_IP(ax2); PRUNE_IP(ax3);                \
    if (DOACC) { SUMS2(sp, spp, ax0, ax1, ax2, ax3); }                         \
    PACK8(ax0, ax1, smem + (DSTB) + oA0);                                      \
    PACK8(ax2, ax3, smem + (DSTB) + oA1); }

#define PW_H1(DSTB, DOACC) {                                                   \
    if (DOACC) { SUMS2(sx, sxx, ax4, ax5, ax6, ax7); }                         \
    PRUNE_IP(ax4); PRUNE_IP(ax5); PRUNE_IP(ax6); PRUNE_IP(ax7);                \
    if (DOACC) { SUMS2(sp, spp, ax4, ax5, ax6, ax7); }                         \
    PACK8(ax4, ax5, smem + (DSTB) + 16384 + oA0);                              \
    PACK8(ax6, ax7, smem + (DSTB) + 16384 + oA1); }

#define MFMA_BLOCK(mh)                                                         \
    __builtin_amdgcn_s_barrier();                                              \
    asm volatile("s_waitcnt lgkmcnt(0)" ::: "memory");                         \
    __builtin_amdgcn_s_setprio(1);                                             \
    _Pragma("unroll") for (int _i = 0; _i < 4; ++_i) {                         \
      _Pragma("unroll") for (int _n = 0; _n < 4; ++_n) {                       \
        acc[(mh)*4+_i][_n] = __builtin_amdgcn_mfma_f32_16x16x32_bf16(          \
            af[_i], bk[_n], acc[(mh)*4+_i][_n], 0, 0, 0); } }                  \
    __builtin_amdgcn_s_setprio(0);                                             \
    __builtin_amdgcn_s_barrier();

__global__ __launch_bounds__(512, 2) void fused_gemm_kernel(
    const float* __restrict__ X,            // [32768][1024] fp32
    const unsigned short* __restrict__ Bw,  // [1024][1024] bf16 (W row-major)
    float* __restrict__ C)                  // [32768][1024] f32
{
    __shared__ char smem[131072];

    const int t = threadIdx.x;
    const int w = t >> 6, l = t & 63;
    const int wm = w >> 2, wn = w & 3;

    const int bid = blockIdx.x;
    const int swz = (bid & 7) * 64 + (bid >> 3);
    const int tile_m = swz >> 2, tile_n = swz & 3;

    // B staging (GLL, proven)
    const int r0 = w * 16 + (l >> 2);
    const int gsrc = (l & 3) ^ ((l >> 3) & 3);
    const unsigned short* bG = Bw + (size_t)(tile_n * 256 + r0) * KD + gsrc * 8;

    // A staging (reg-staged from x fp32; mapping proven correct in round 3)
    const int arow = t >> 1;
    const float* xT = X + (size_t)(tile_m * 256 + arow) * KD + (t & 1) * 16;
    const int q0g = (t & 1) * 2;
    const int rx  = (t >> 2) & 3;
    const int oA0 = arow * 64 + ((q0g       ^ rx) * 16);
    const int oA1 = arow * 64 + (((q0g | 1) ^ rx) * 16);

    // reader bases
    const int gq  = (l >> 4) ^ ((l >> 1) & 3);
    const int aR0 = (wm * 128 + (l & 15)) * 64 + gq * 16;
    const int bR0 = (wn * 64 + (l & 15)) * 64 + gq * 16;

    f32x4 acc[8][4] = {};
    bf16x8 af[4], bk[4];
    float4 ax0, ax1, ax2, ax3, ax4, ax5, ax6, ax7;
    float sx = 0.f, sxx = 0.f, sp = 0.f, spp = 0.f;

    // ---- prologue (tile 0): queue sim [AH0 AH1 Bk0 Bk1] ----
    AXH0(0); AXH1(0);
    BSTAGE(0, 0, 0);
    BSTAGE(0, 1, 0);
    VMW(8);                    // AH0 done
    PW_H0(0, 1);
    VMW(4);                    // AH1 done
    PW_H1(0, 1);
    VMW(2);                    // B kh0 done (leaves B kh1 in flight)
    __syncthreads();

    // ---- main loop; invariant at q0: 2 outstanding = B kh1(tt) ----
    for (int tt = 0; tt < 16; ++tt) {
        const int bufc = (tt & 1) << 15;
        const int bufn = bufc ^ 32768;
        const int ktoff = ((tt + 1) & 15) * 64;
        const bool doacc = (tt != 15);

        // q0 (mh0,ks0)
        LOADA(bufc, 0, 0); LOADB(bufc, 0);
        AXH0(ktoff);                         // [Bk1(2), AH0(4)]
        VMW(4);                              // drain Bk1(tt)
        MFMA_BLOCK(0);

        // q1 (mh0,ks1)
        LOADA(bufc, 0, 1); LOADB(bufc, 1);
        AXH1(ktoff);                         // [AH0, AH1]
        BSTAGE(bufn, 0, ktoff);              // [AH0, AH1, Bk0']
        MFMA_BLOCK(0);

        // q2 (mh1,ks0)
        LOADA(bufc, 1, 0); LOADB(bufc, 0);
        VMW(6);                              // drain AH0
        PW_H0(bufn, doacc);
        MFMA_BLOCK(1);

        // q3 (mh1,ks1)
        LOADA(bufc, 1, 1); LOADB(bufc, 1);
        VMW(2);                              // drain AH1 (leaves Bk0')
        PW_H1(bufn, doacc);
        BSTAGE(bufn, 1, ktoff);              // [Bk0', Bk1']
        VMW(2);                              // drain Bk0' -> invariant
        MFMA_BLOCK(1);
    }

    // ---- epilogue: per-row v, then scaled C write ----
    __syncthreads();
    float SX  = sx  + __shfl_xor(sx,  1);
    float SXX = sxx + __shfl_xor(sxx, 1);
    float SP  = sp  + __shfl_xor(sp,  1);
    float SPP = spp + __shfl_xor(spp, 1);
    float* vbuf = (float*)(smem + 32768);
    if ((t & 1) == 0) {
        const float var_x = (SXX - SX * SX * (1.0f / 1024.0f)) * (1.0f / 1023.0f);
        float var_p = (SPP - SP * SP * (1.0f / 1024.0f)) * (1.0f / 1023.0f);
        var_p = fmaxf(var_p, 1e-9f);
        vbuf[arow] = sqrtf(var_x / var_p);
    }
    __syncthreads();

    float* Cp = C + (size_t)(tile_m * 256 + wm * 128 + ((l >> 4) * 4)) * ND
                  + tile_n * 256 + wn * 64 + (l & 15);
    #pragma unroll
    for (int m = 0; m < 8; ++m) {
        const float4 vm = *(const float4*)&vbuf[wm * 128 + m * 16 + (l >> 4) * 4];
        #pragma unroll
        for (int n = 0; n < 4; ++n) {
            Cp[(size_t)(m * 16 + 0) * ND + n * 16] = acc[m][n][0] * vm.x;
            Cp[(size_t)(m * 16 + 1) * ND + n * 16] = acc[m][n][1] * vm.y;
            Cp[(size_t)(m * 16 + 2) * ND + n * 16] = acc[m][n][2] * vm.z;
            Cp[(size_t)(m * 16 + 3) * ND + n * 16] = acc[m][n][3] * vm.w;
        }
    }
}

extern "C" void kernel_launch(void* const* d_in, const int* in_sizes, int n_in,
                              void* d_out, int out_size, void* d_ws, size_t ws_size,
                              hipStream_t stream) {
    const float* x  = (const float*)d_in[0];   // [4,8192,1024] fp32
    const float* wt = (const float*)d_in[1];   // [1024,1024] fp32
    float* out = (float*)d_out;                // [4,8192,1024] fp32

    unsigned short* Wbf = (unsigned short*)d_ws;   // 2 MiB

    wconv_kernel<<<1024, 256, 0, stream>>>(wt, Wbf);
    fused_gemm_kernel<<<512, 512, 0, stream>>>(x, Wbf, out);
}

// Round 5
// 288.883 us; speedup vs baseline: 1.9070x; 1.9070x over previous
//
#include <hip/hip_runtime.h>
#include <hip/hip_bf16.h>
#include <stdint.h>

typedef __attribute__((ext_vector_type(8))) __bf16 bf16x8;
typedef __attribute__((ext_vector_type(4))) float f32x4;

static __device__ __forceinline__ unsigned short f2bf(float f) {
    unsigned int u = __float_as_uint(f);
    unsigned int r = (u + 0x7fffu + ((u >> 16) & 1u)) >> 16;
    return (unsigned short)r;
}

// ---------------- Kernel 1: weight fp32 -> bf16 ----------------
__global__ __launch_bounds__(256) void wconv_kernel(
    const float* __restrict__ w, unsigned short* __restrict__ wb)
{
    const int i = blockIdx.x * 256 + threadIdx.x;
    const float4 v = ((const float4*)w)[i];
    ushort4 o;
    o.x = f2bf(v.x); o.y = f2bf(v.y); o.z = f2bf(v.z); o.w = f2bf(v.w);
    ((ushort4*)wb)[i] = o;
}

// ---------------- Kernel 2: fused prune + variance-scale + 256x256x64 GEMM ----------------
// Quarter ping-pong A-prefetch: 2 banks x 2 float4 (16 regs total, vs 32 that spilled).
// Each phase: issue one quarter (2 loads) into free bank, process the other bank
// (sums + 2:4 prune + bf16 pack + 1 swizzled ds_write_b128). All 4 quarters of tile s
// processed during tile s-1. B staged via global_load_lds (round-2-proven path).
#define KD 1024
#define ND 1024

#define GLL16(gp, lp)                                                          \
    __builtin_amdgcn_global_load_lds(                                          \
        (const __attribute__((address_space(1))) void*)(gp),                   \
        (__attribute__((address_space(3))) void*)(lp), 16, 0, 0)

#define VMW(n) asm volatile("s_waitcnt vmcnt(" #n ")" ::: "memory")

#define BSTAGE(BUFB, kh, ktoff) {                                              \
    const unsigned short* _s = bG + (ktoff) + (kh) * 32;                       \
    char* _dp = smem + 65536 + (BUFB) + (kh) * 16384 + w * 1024;               \
    GLL16(_s, _dp); GLL16(_s + 128 * KD, _dp + 8192); }

#define LOADA(BUFB, mh, ks) {                                                  \
    const char* _ab = smem + (BUFB) + (ks) * 16384 + aR0 + (mh) * 4096;        \
    af[0] = *(const bf16x8*)(_ab);                                             \
    af[1] = *(const bf16x8*)(_ab + 1024);                                      \
    af[2] = *(const bf16x8*)(_ab + 2048);                                      \
    af[3] = *(const bf16x8*)(_ab + 3072); }

#define LOADB(BUFB, ks) {                                                      \
    const char* _bb = smem + 65536 + (BUFB) + (ks) * 16384 + bR0;              \
    bk[0] = *(const bf16x8*)(_bb);                                             \
    bk[1] = *(const bf16x8*)(_bb + 1024);                                      \
    bk[2] = *(const bf16x8*)(_bb + 2048);                                      \
    bk[3] = *(const bf16x8*)(_bb + 3072); }

// issue one quarter (8 floats) into a bank
#define ISSUE_Q(g0, g1, foff) {                                                \
    g0 = *(const float4*)(xT + (foff));                                        \
    g1 = *(const float4*)(xT + (foff) + 4); }

#define PRUNE_IP(g) {                                                          \
    const float b0 = fabsf(g.x), b1 = fabsf(g.y), b2 = fabsf(g.z), b3 = fabsf(g.w); \
    const int r0 = (b1 >  b0) + (b2 >  b0) + (b3 >  b0);                       \
    const int r1 = (b0 >= b1) + (b2 >  b1) + (b3 >  b1);                       \
    const int r2 = (b0 >= b2) + (b1 >= b2) + (b3 >  b2);                       \
    const int r3 = (b0 >= b3) + (b1 >= b3) + (b2 >= b3);                       \
    g.x = (r0 < 2) ? g.x : 0.0f;                                               \
    g.y = (r1 < 2) ? g.y : 0.0f;                                               \
    g.z = (r2 < 2) ? g.z : 0.0f;                                               \
    g.w = (r3 < 2) ? g.w : 0.0f; }

#define SUMSQ(sa, sb, a, b) {                                                  \
    sa += ((a.x + a.y) + (a.z + a.w)) + ((b.x + b.y) + (b.z + b.w));           \
    sb += (a.x*a.x + a.y*a.y + a.z*a.z + a.w*a.w)                              \
        + (b.x*b.x + b.y*b.y + b.z*b.z + b.w*b.w); }

#define PACK8(pa, pb, dstb) {                                                  \
    union { ushort h[8]; uint4 q; } _k;                                        \
    _k.h[0] = f2bf(pa.x); _k.h[1] = f2bf(pa.y);                                \
    _k.h[2] = f2bf(pa.z); _k.h[3] = f2bf(pa.w);                                \
    _k.h[4] = f2bf(pb.x); _k.h[5] = f2bf(pb.y);                                \
    _k.h[6] = f2bf(pb.z); _k.h[7] = f2bf(pb.w);                                \
    *(uint4*)(dstb) = _k.q; }

// process one quarter: sums(raw) -> prune -> sums(pruned) -> pack -> ds_write
#define PROC(g0, g1, DSTB, kh, OW, DOACC) {                                    \
    if (DOACC) { SUMSQ(sx, sxx, g0, g1); }                                     \
    PRUNE_IP(g0); PRUNE_IP(g1);                                                \
    if (DOACC) { SUMSQ(sp, spp, g0, g1); }                                     \
    PACK8(g0, g1, smem + (DSTB) + (kh) * 16384 + (OW)); }

#define MFMA_BLOCK(mh)                                                         \
    __builtin_amdgcn_s_barrier();                                              \
    asm volatile("s_waitcnt lgkmcnt(0)" ::: "memory");                         \
    __builtin_amdgcn_s_setprio(1);                                             \
    _Pragma("unroll") for (int _i = 0; _i < 4; ++_i) {                         \
      _Pragma("unroll") for (int _n = 0; _n < 4; ++_n) {                       \
        acc[(mh)*4+_i][_n] = __builtin_amdgcn_mfma_f32_16x16x32_bf16(          \
            af[_i], bk[_n], acc[(mh)*4+_i][_n], 0, 0, 0); } }                  \
    __builtin_amdgcn_s_setprio(0);                                             \
    __builtin_amdgcn_s_barrier();

__global__ __launch_bounds__(512, 2) void fused_gemm_kernel(
    const float* __restrict__ X,            // [32768][1024] fp32
    const unsigned short* __restrict__ Bw,  // [1024][1024] bf16 (W row-major)
    float* __restrict__ C)                  // [32768][1024] f32
{
    __shared__ char smem[131072];

    const int t = threadIdx.x;
    const int w = t >> 6, l = t & 63;
    const int wm = w >> 2, wn = w & 3;

    const int bid = blockIdx.x;
    const int swz = (bid & 7) * 64 + (bid >> 3);
    const int tile_m = swz >> 2, tile_n = swz & 3;

    // B staging (GLL, proven)
    const int r0 = w * 16 + (l >> 2);
    const int gsrc = (l & 3) ^ ((l >> 3) & 3);
    const unsigned short* bG = Bw + (size_t)(tile_n * 256 + r0) * KD + gsrc * 8;

    // A staging (reg-staged from x fp32)
    const int arow = t >> 1;                    // row 0..255
    const float* xT = X + (size_t)(tile_m * 256 + arow) * KD + (t & 1) * 16;
    const int q0g = (t & 1) * 2;                // thread's granule pair base
    const int rx  = (t >> 2) & 3;               // (arow>>1)&3 row-XOR swizzle
    const int oW0 = arow * 64 + ((q0g       ^ rx) * 16);
    const int oW1 = arow * 64 + (((q0g | 1) ^ rx) * 16);

    // reader bases
    const int gq  = (l >> 4) ^ ((l >> 1) & 3);
    const int aR0 = (wm * 128 + (l & 15)) * 64 + gq * 16;
    const int bR0 = (wn * 64 + (l & 15)) * 64 + gq * 16;

    f32x4 acc[8][4] = {};
    bf16x8 af[4], bk[4];
    float4 axA0, axA1, axB0, axB1;              // two ping-pong banks, 8 regs each
    float sx = 0.f, sxx = 0.f, sp = 0.f, spp = 0.f;

    // ---- prologue: tile 0 -> buf0, then seed invariant ----
    ISSUE_Q(axA0, axA1, 0);                 // Q0
    ISSUE_Q(axB0, axB1, 8);                 // Q1
    BSTAGE(0, 0, 0);                        // B kh0(0)
    BSTAGE(0, 1, 0);                        // B kh1(0)   queue: [Q0,Q1,b0,b1]=8
    VMW(6);  PROC(axA0, axA1, 0, 0, oW0, 1);
    VMW(4);  PROC(axB0, axB1, 0, 0, oW1, 1);
    ISSUE_Q(axA0, axA1, 32);                // Q2
    ISSUE_Q(axB0, axB1, 40);                // Q3   queue: [b0,b1,Q2,Q3]=8
    VMW(2);  PROC(axA0, axA1, 0, 1, oW0, 1);
    VMW(0);  PROC(axB0, axB1, 0, 1, oW1, 1);
    ISSUE_Q(axA0, axA1, 64);                // IQ0 for tile 1  queue: [IQ0]=2
    __syncthreads();

    // ---- main loop; entering q0: queue = [(b1', IQ0)] <= 4 outstanding ----
    for (int tt = 0; tt < 16; ++tt) {
        const int bufc = (tt & 1) << 15;
        const int bufn = bufc ^ 32768;
        const int kt1 = ((tt + 1) & 15) * 64;    // tile tt+1 base (floats)
        const int kt2 = ((tt + 2) & 15) * 64;    // tile tt+2 base
        const bool doacc = (tt != 15);           // processing tile tt+1; skip wrap

        // q0 (mh0,ks0): process Q0(bank A) -> bufn kh0; issue Q1 -> bank B
        LOADA(bufc, 0, 0); LOADB(bufc, 0);
        ISSUE_Q(axB0, axB1, kt1 + 8);
        VMW(2);                                   // drains b1(tt) + IQ0
        PROC(axA0, axA1, bufn, 0, oW0, doacc);
        MFMA_BLOCK(0);

        // q1 (mh0,ks1): process Q1(B) -> kh0; issue Q2 -> A; stage B kh0(tt+1)
        LOADA(bufc, 0, 1); LOADB(bufc, 1);
        ISSUE_Q(axA0, axA1, kt1 + 32);
        BSTAGE(bufn, 0, kt1);
        VMW(4);                                   // drains Q1 loads
        PROC(axB0, axB1, bufn, 0, oW1, doacc);
        MFMA_BLOCK(0);

        // q2 (mh1,ks0): process Q2(A) -> kh1; issue Q3 -> B
        LOADA(bufc, 1, 0); LOADB(bufc, 0);
        ISSUE_Q(axB0, axB1, kt1 + 40);
        VMW(4);                                   // drains Q2 loads
        PROC(axA0, axA1, bufn, 1, oW0, doacc);
        MFMA_BLOCK(1);

        // q3 (mh1,ks1): process Q3(B) -> kh1; stage B kh1(tt+1); issue Q0(tt+2) -> A
        LOADA(bufc, 1, 1); LOADB(bufc, 1);
        BSTAGE(bufn, 1, kt1);
        ISSUE_Q(axA0, axA1, kt2);
        VMW(4);                                   // drains b0(tt+1) + Q3 loads
        PROC(axB0, axB1, bufn, 1, oW1, doacc);
        MFMA_BLOCK(1);
    }

    // ---- epilogue: retire dangling prefetch, per-row v, scaled C write ----
    VMW(0);
    __syncthreads();
    float SX  = sx  + __shfl_xor(sx,  1);
    float SXX = sxx + __shfl_xor(sxx, 1);
    float SP  = sp  + __shfl_xor(sp,  1);
    float SPP = spp + __shfl_xor(spp, 1);
    float* vbuf = (float*)(smem + 32768);
    if ((t & 1) == 0) {
        const float var_x = (SXX - SX * SX * (1.0f / 1024.0f)) * (1.0f / 1023.0f);
        float var_p = (SPP - SP * SP * (1.0f / 1024.0f)) * (1.0f / 1023.0f);
        var_p = fmaxf(var_p, 1e-9f);
        vbuf[arow] = sqrtf(var_x / var_p);
    }
    __syncthreads();

    float* Cp = C + (size_t)(tile_m * 256 + wm * 128 + ((l >> 4) * 4)) * ND
                  + tile_n * 256 + wn * 64 + (l & 15);
    #pragma unroll
    for (int m = 0; m < 8; ++m) {
        const float4 vm = *(const float4*)&vbuf[wm * 128 + m * 16 + (l >> 4) * 4];
        #pragma unroll
        for (int n = 0; n < 4; ++n) {
            Cp[(size_t)(m * 16 + 0) * ND + n * 16] = acc[m][n][0] * vm.x;
            Cp[(size_t)(m * 16 + 1) * ND + n * 16] = acc[m][n][1] * vm.y;
            Cp[(size_t)(m * 16 + 2) * ND + n * 16] = acc[m][n][2] * vm.z;
            Cp[(size_t)(m * 16 + 3) * ND + n * 16] = acc[m][n][3] * vm.w;
        }
    }
}

extern "C" void kernel_launch(void* const* d_in, const int* in_sizes, int n_in,
                              void* d_out, int out_size, void* d_ws, size_t ws_size,
                              hipStream_t stream) {
    const float* x  = (const float*)d_in[0];   // [4,8192,1024] fp32
    const float* wt = (const float*)d_in[1];   // [1024,1024] fp32
    float* out = (float*)d_out;                // [4,8192,1024] fp32

    unsigned short* Wbf = (unsigned short*)d_ws;   // 2 MiB

    wconv_kernel<<<1024, 256, 0, stream>>>(wt, Wbf);
    fused_gemm_kernel<<<512, 512, 0, stream>>>(x, Wbf, out);
}

// Round 6
// 236.901 us; speedup vs baseline: 2.3254x; 1.2194x over previous
//
#include <hip/hip_runtime.h>
#include <hip/hip_bf16.h>
#include <stdint.h>

typedef __attribute__((ext_vector_type(8))) __bf16 bf16x8;
typedef __attribute__((ext_vector_type(4))) float f32x4;

static __device__ __forceinline__ unsigned short f2bf(float f) {
    unsigned int u = __float_as_uint(f);
    unsigned int r = (u + 0x7fffu + ((u >> 16) & 1u)) >> 16;
    return (unsigned short)r;
}

// ---------------- Kernel 1: weight fp32 -> bf16 ----------------
__global__ __launch_bounds__(256) void wconv_kernel(
    const float* __restrict__ w, unsigned short* __restrict__ wb)
{
    const int i = blockIdx.x * 256 + threadIdx.x;
    const float4 v = ((const float4*)w)[i];
    ushort4 o;
    o.x = f2bf(v.x); o.y = f2bf(v.y); o.z = f2bf(v.z); o.w = f2bf(v.w);
    ((ushort4*)wb)[i] = o;
}

// ---------------- Kernel 2: fused prune+var-scale+GEMM, 128x128x64 tile ----------------
// 256 threads (4 waves 2x2), 64KB LDS -> 2 blocks/CU (the round-5 fix: co-resident
// blocks hide each other's barrier/VALU/latency stalls).
// LDS: A buf0 @0, A buf1 @16384, B buf0 @32768, B buf1 @49152.
//      Each buf: [kh=2][128 rows][4 granules of 16B], granule swizzled g' = g ^ (row&3).
// Per tile (BK=64): 2 phases (ks=0,1). Phase: ds_read frags; GLL-stage B half(tt+1);
// barrier; MFMA x16; counted-vmcnt PROC of two A-quarters (tile tt+1) incl. variance
// sums; issue next 2 quarters; lgkm-seal; barrier.
#define KD 1024
#define ND 1024

#define GLL16(gp, lp)                                                          \
    __builtin_amdgcn_global_load_lds(                                          \
        (const __attribute__((address_space(1))) void*)(gp),                   \
        (__attribute__((address_space(3))) void*)(lp), 16, 0, 0)

#define VMW(n) asm volatile("s_waitcnt vmcnt(" #n ")" ::: "memory")
#define LGKM0  asm volatile("s_waitcnt lgkmcnt(0)" ::: "memory")

#define BSTAGE(BUFB, kh, kte) {                                                \
    GLL16(bG0 + (kte) + (kh) * 32, smem + 32768 + (BUFB) + (kh) * 8192 + w * 2048); \
    GLL16(bG1 + (kte) + (kh) * 32, smem + 32768 + (BUFB) + (kh) * 8192 + w * 2048 + 1024); }

#define LOADA(ABUF, ks) {                                                      \
    const char* _ab = smem + (ABUF) + (ks) * 8192 + aRb;                       \
    af[0] = *(const bf16x8*)(_ab);                                             \
    af[1] = *(const bf16x8*)(_ab + 1024);                                      \
    af[2] = *(const bf16x8*)(_ab + 2048);                                      \
    af[3] = *(const bf16x8*)(_ab + 3072); }

#define LOADB(BUFB, ks) {                                                      \
    const char* _bb = smem + 32768 + (BUFB) + (ks) * 8192 + bRb;               \
    bk[0] = *(const bf16x8*)(_bb);                                             \
    bk[1] = *(const bf16x8*)(_bb + 1024);                                      \
    bk[2] = *(const bf16x8*)(_bb + 2048);                                      \
    bk[3] = *(const bf16x8*)(_bb + 3072); }

#define ISSUE(g0, g1, foff) {                                                  \
    g0 = *(const float4*)(xT + (foff));                                        \
    g1 = *(const float4*)(xT + (foff) + 4); }

#define PRUNE_IP(g) {                                                          \
    const float b0 = fabsf(g.x), b1 = fabsf(g.y), b2 = fabsf(g.z), b3 = fabsf(g.w); \
    const int r0 = (b1 >  b0) + (b2 >  b0) + (b3 >  b0);                       \
    const int r1 = (b0 >= b1) + (b2 >  b1) + (b3 >  b1);                       \
    const int r2 = (b0 >= b2) + (b1 >= b2) + (b3 >  b2);                       \
    const int r3 = (b0 >= b3) + (b1 >= b3) + (b2 >= b3);                       \
    g.x = (r0 < 2) ? g.x : 0.0f;                                               \
    g.y = (r1 < 2) ? g.y : 0.0f;                                               \
    g.z = (r2 < 2) ? g.z : 0.0f;                                               \
    g.w = (r3 < 2) ? g.w : 0.0f; }

#define SUMSQ(sa, sb, a, b) {                                                  \
    sa += ((a.x + a.y) + (a.z + a.w)) + ((b.x + b.y) + (b.z + b.w));           \
    sb += (a.x*a.x + a.y*a.y + a.z*a.z + a.w*a.w)                              \
        + (b.x*b.x + b.y*b.y + b.z*b.z + b.w*b.w); }

// process one quarter (8 floats): sums(raw)->prune->sums(pruned)->cast->1x ds_write_b128
#define PROCQ(g0, g1, ABUF, q, DOACC) {                                        \
    if (DOACC) { SUMSQ(sx, sxx, g0, g1); }                                     \
    PRUNE_IP(g0); PRUNE_IP(g1);                                                \
    if (DOACC) { SUMSQ(sp, spp, g0, g1); }                                     \
    bf16x8 _pk;                                                                \
    _pk[0] = (__bf16)g0.x; _pk[1] = (__bf16)g0.y;                              \
    _pk[2] = (__bf16)g0.z; _pk[3] = (__bf16)g0.w;                              \
    _pk[4] = (__bf16)g1.x; _pk[5] = (__bf16)g1.y;                              \
    _pk[6] = (__bf16)g1.z; _pk[7] = (__bf16)g1.w;                              \
    *(bf16x8*)(smem + (ABUF) + aWb + (((q) ^ rs) * 16)) = _pk; }

#define MFMA16                                                                 \
    _Pragma("unroll") for (int _m = 0; _m < 4; ++_m) {                         \
      _Pragma("unroll") for (int _n = 0; _n < 4; ++_n) {                       \
        acc[_m][_n] = __builtin_amdgcn_mfma_f32_16x16x32_bf16(                 \
            af[_m], bk[_n], acc[_m][_n], 0, 0, 0); } }

// One phase. ks: k-half for MFMA reads AND the B-half staged for tile tt+1.
// FIFO invariant entering phase: 6 outstanding [bhalf(2), Qa(2), Qb(2)].
#define PHASE(BUFC, BUFN, ks, KTE, QA, QB, IOFFA, IOFFB, DA) {                 \
    bf16x8 af[4], bk[4];                                                       \
    LOADA(BUFC, ks); LOADB(BUFC, ks);                                          \
    BSTAGE(BUFN, ks, KTE);                                                     \
    __builtin_amdgcn_s_barrier();                                              \
    LGKM0;                                                                     \
    __builtin_amdgcn_s_setprio(1);                                             \
    MFMA16;                                                                    \
    __builtin_amdgcn_s_setprio(0);                                             \
    VMW(4);                                                                    \
    PROCQ(axA0, axA1, BUFN, QA, DA);                                           \
    VMW(2);                                                                    \
    PROCQ(axB0, axB1, BUFN, QB, DA);                                           \
    ISSUE(axA0, axA1, IOFFA);                                                  \
    ISSUE(axB0, axB1, IOFFB);                                                  \
    LGKM0;                                                                     \
    __builtin_amdgcn_s_barrier(); }

__global__ __launch_bounds__(256, 2) void fused_gemm_kernel(
    const float* __restrict__ X,            // [32768][1024] fp32
    const unsigned short* __restrict__ Bw,  // [1024][1024] bf16 (W row-major)
    float* __restrict__ C)                  // [32768][1024] f32
{
    __shared__ char smem[65536];

    const int t = threadIdx.x;
    const int w = t >> 6, l = t & 63;
    const int wm = w >> 1, wn = w & 1;

    // XCD swizzle (2048 % 8 == 0): each XCD gets 32 consecutive m-panels x all 8 n
    const int bid = blockIdx.x;
    const int swz = (bid & 7) * 256 + (bid >> 3);
    const int tile_m = swz >> 3, tile_n = swz & 7;

    // ---- B staging: 2 GLL/wave/half; dest linear, source inverse-swizzled ----
    const int R0 = w * 32 + (l >> 2);          // rows R0, R0+16 for the 2 GLLs
    const int gsrc = (l & 3) ^ ((l >> 2) & 3);
    const unsigned short* bG0 = Bw + (size_t)(tile_n * 128 + R0) * KD + gsrc * 8;
    const unsigned short* bG1 = bG0 + (size_t)16 * KD;

    // ---- A source: thread owns row r, k-half h (32 floats/tile, 4 quarters) ----
    const int r = t >> 1, h = t & 1;
    const float* xT = X + (size_t)(tile_m * 128 + r) * KD + h * 32;
    const int aWb = h * 8192 + r * 64;         // byte base within an A buf
    const int rs  = r & 3;                     // granule XOR swizzle

    // ---- fragment readers (granule g at position g ^ (row&3)) ----
    const int gg  = ((l >> 4) ^ (l & 3)) * 16;
    const int aRb = (wm * 64 + (l & 15)) * 64 + gg;
    const int bRb = (wn * 64 + (l & 15)) * 64 + gg;

    f32x4 acc[4][4] = {};
    float4 axA0, axA1, axB0, axB1;             // two quarter banks (16 VGPR)
    float sx = 0.f, sxx = 0.f, sp = 0.f, spp = 0.f;

    // ---- prologue: tile 0 -> buf0; seed quarters Q0,Q1 of tile 1 ----
    ISSUE(axA0, axA1, 0);                      // t0 Q0
    ISSUE(axB0, axB1, 8);                      // t0 Q1
    BSTAGE(0, 0, 0);                           // B(0) kh0
    BSTAGE(0, 1, 0);                           // B(0) kh1   queue=8
    VMW(6); PROCQ(axA0, axA1, 0, 0, 1);
    VMW(4); PROCQ(axB0, axB1, 0, 1, 1);
    ISSUE(axA0, axA1, 16);                     // t0 Q2
    ISSUE(axB0, axB1, 24);                     // t0 Q3   queue=[b0,b1,Q2,Q3]=8
    VMW(2); PROCQ(axA0, axA1, 0, 2, 1);
    VMW(0); PROCQ(axB0, axB1, 0, 3, 1);
    ISSUE(axA0, axA1, 64);                     // tile1 Q0
    ISSUE(axB0, axB1, 72);                     // tile1 Q1
    __syncthreads();                           // full drain + seal (prologue only)

    // ---- main loop: 16 tiles x 2 phases ----
    for (int tt = 0; tt < 16; ++tt) {
        const int bufc = (tt & 1) * 16384;
        const int bufn = bufc ^ 16384;
        const int kte1 = ((tt + 1) & 15) * 64; // tile tt+1 k-offset (elements/floats)
        const int kte2 = ((tt + 2) & 15) * 64;
        const bool da = (tt != 15);            // tt=15 PROCs wrapped tile-0: skip sums

        // p0: MFMA ks0; stage B kh0(tt+1); PROC Q0,Q1(tt+1); issue Q2,Q3(tt+1)
        PHASE(bufc, bufn, 0, kte1, 0, 1, kte1 + 16, kte1 + 24, da);
        // p1: MFMA ks1; stage B kh1(tt+1); PROC Q2,Q3(tt+1); issue Q0,Q1(tt+2)
        PHASE(bufc, bufn, 1, kte1, 2, 3, kte2 + 0, kte2 + 8, da);
    }

    // ---- epilogue: per-row v, scaled C write ----
    VMW(0);
    __syncthreads();
    float SX  = sx  + __shfl_xor(sx,  1);
    float SXX = sxx + __shfl_xor(sxx, 1);
    float SP  = sp  + __shfl_xor(sp,  1);
    float SPP = spp + __shfl_xor(spp, 1);
    float* vbuf = (float*)smem;                // A buf0: dead after loop
    if (h == 0) {
        const float var_x = (SXX - SX * SX * (1.0f / 1024.0f)) * (1.0f / 1023.0f);
        float var_p = (SPP - SP * SP * (1.0f / 1024.0f)) * (1.0f / 1023.0f);
        var_p = fmaxf(var_p, 1e-9f);
        vbuf[r] = sqrtf(var_x / var_p);
    }
    __syncthreads();

    float* Cp = C + (size_t)(tile_m * 128 + wm * 64 + ((l >> 4) * 4)) * ND
                  + tile_n * 128 + wn * 64 + (l & 15);
    #pragma unroll
    for (int m = 0; m < 4; ++m) {
        const float4 vm = *(const float4*)&vbuf[wm * 64 + m * 16 + (l >> 4) * 4];
        #pragma unroll
        for (int n = 0; n < 4; ++n) {
            Cp[(size_t)(m * 16 + 0) * ND + n * 16] = acc[m][n][0] * vm.x;
            Cp[(size_t)(m * 16 + 1) * ND + n * 16] = acc[m][n][1] * vm.y;
            Cp[(size_t)(m * 16 + 2) * ND + n * 16] = acc[m][n][2] * vm.z;
            Cp[(size_t)(m * 16 + 3) * ND + n * 16] = acc[m][n][3] * vm.w;
        }
    }
}

extern "C" void kernel_launch(void* const* d_in, const int* in_sizes, int n_in,
                              void* d_out, int out_size, void* d_ws, size_t ws_size,
                              hipStream_t stream) {
    const float* x  = (const float*)d_in[0];   // [4,8192,1024] fp32
    const float* wt = (const float*)d_in[1];   // [1024,1024] fp32
    float* out = (float*)d_out;                // [4,8192,1024] fp32

    unsigned short* Wbf = (unsigned short*)d_ws;   // 2 MiB

    wconv_kernel<<<1024, 256, 0, stream>>>(wt, Wbf);
    fused_gemm_kernel<<<2048, 256, 0, stream>>>(x, Wbf, out);
}

// Round 9
// 123.870 us; speedup vs baseline: 4.4474x; 1.9125x over previous
//
#include <hip/hip_runtime.h>
#include <hip/hip_bf16.h>
#include <stdint.h>

typedef __attribute__((ext_vector_type(8))) __bf16 bf16x8;
typedef __attribute__((ext_vector_type(4))) float f32x4;

static __device__ __forceinline__ unsigned short f2bf(float f) {
    unsigned int u = __float_as_uint(f);
    unsigned int r = (u + 0x7fffu + ((u >> 16) & 1u)) >> 16;
    return (unsigned short)r;
}

// ---------------- Kernel 1: 2:4 prune + variance-ratio scale (+ weight conv) ----------------
// Blocks 0..32767: one row of x each. Blocks 32768..33791: weight fp32->bf16.
__global__ __launch_bounds__(256) void prune_scale_kernel(
    const float* __restrict__ x, unsigned short* __restrict__ a,
    const float* __restrict__ wsrc, unsigned short* __restrict__ wdst)
{
    const int bid = blockIdx.x;
    const int t = threadIdx.x;

    if (bid >= 32768) {                        // ---- weight conversion part ----
        const int i = (bid - 32768) * 256 + t; // 4 elems per thread
        const float4 v = ((const float4*)wsrc)[i];
        ushort4 o;
        o.x = f2bf(v.x); o.y = f2bf(v.y); o.z = f2bf(v.z); o.w = f2bf(v.w);
        ((ushort4*)wdst)[i] = o;
        return;
    }

    const int row = bid;
    const float4 g = ((const float4*)(x + (size_t)row * 1024))[t];

    const float a0 = fabsf(g.x), a1 = fabsf(g.y), a2 = fabsf(g.z), a3 = fabsf(g.w);
    // rank via stable tie-break (lower index wins) -- matches jax.lax.top_k
    const int r0 = (a1 > a0) + (a2 > a0) + (a3 > a0);
    const int r1 = (a0 >= a1) + (a2 > a1) + (a3 > a1);
    const int r2 = (a0 >= a2) + (a1 >= a2) + (a3 > a2);
    const int r3 = (a0 >= a3) + (a1 >= a3) + (a2 >= a3);
    const float p0 = (r0 < 2) ? g.x : 0.0f;
    const float p1 = (r1 < 2) ? g.y : 0.0f;
    const float p2 = (r2 < 2) ? g.z : 0.0f;
    const float p3 = (r3 < 2) ? g.w : 0.0f;

    float sx  = g.x + g.y + g.z + g.w;
    float sxx = g.x*g.x + g.y*g.y + g.z*g.z + g.w*g.w;
    float sp  = p0 + p1 + p2 + p3;
    float spp = p0*p0 + p1*p1 + p2*p2 + p3*p3;

    #pragma unroll
    for (int off = 32; off > 0; off >>= 1) {
        sx  += __shfl_down(sx,  off);
        sxx += __shfl_down(sxx, off);
        sp  += __shfl_down(sp,  off);
        spp += __shfl_down(spp, off);
    }
    __shared__ float red[4][4];
    __shared__ float vsh;
    const int lane = t & 63, w = t >> 6;
    if (lane == 0) { red[w][0] = sx; red[w][1] = sxx; red[w][2] = sp; red[w][3] = spp; }
    __syncthreads();
    if (t == 0) {
        float SX = 0.f, SXX = 0.f, SP = 0.f, SPP = 0.f;
        #pragma unroll
        for (int i = 0; i < 4; ++i) { SX += red[i][0]; SXX += red[i][1]; SP += red[i][2]; SPP += red[i][3]; }
        const float D = 1024.0f, DM1 = 1023.0f;
        const float var_x = (SXX - SX * SX / D) / DM1;
        float var_p = (SPP - SP * SP / D) / DM1;
        var_p = fmaxf(var_p, 1e-9f);
        vsh = sqrtf(var_x / var_p);
    }
    __syncthreads();
    const float v = vsh;

    ushort4 o;
    o.x = f2bf(v * p0); o.y = f2bf(v * p1); o.z = f2bf(v * p2); o.w = f2bf(v * p3);
    ((ushort4*)(a + (size_t)row * 1024))[t] = o;
}

// ---------------- Kernel 2: 256x256x64 deep-pipelined bf16 GEMM (B^T), fp32 out ----------------
// Round-2-proven macros (full-kh staging units: 2 GLLs cover all 256 rows -- the round-8
// bug was per-row-half units whose land-time missed wm=1 waves' reads). Reordered staging
// + counted vmcnt so every drained load is >=2 phases old:
//   q0: stage A-kh0', VMW(2)  (retires Bk1(tt),Ak1(tt) -- ages 3,2 phases)
//   q1: stage B-kh0'+B-kh1'
//   q2: stage A-kh1'
//   q3: VMW(4)                (retires Ak0',Bk0' -- ages 3,2 phases)
#define KD 1024
#define ND 1024

#define GLL16(gp, lp)                                                          \
    __builtin_amdgcn_global_load_lds(                                          \
        (const __attribute__((address_space(1))) void*)(gp),                   \
        (__attribute__((address_space(3))) void*)(lp), 16, 0, 0)

#define VMW(n) asm volatile("s_waitcnt vmcnt(" #n ")" ::: "memory")

#define ASTAGE(bufx, kh, kt) {                                                 \
    const unsigned short* _s = aG + (size_t)(kt) * 64 + (kh) * 32;             \
    char* _dp = smem + (bufx) * 32768 + (kh) * 16384 + w * 1024;               \
    GLL16(_s, _dp); GLL16(_s + 128 * KD, _dp + 8192); }

#define BSTAGE(bufx, kh, kt) {                                                 \
    const unsigned short* _s = bG + (size_t)(kt) * 64 + (kh) * 32;             \
    char* _dp = smem + 65536 + (bufx) * 32768 + (kh) * 16384 + w * 1024;       \
    GLL16(_s, _dp); GLL16(_s + 8192); }

#undef BSTAGE
#define BSTAGE(bufx, kh, kt) {                                                 \
    const unsigned short* _s = bG + (size_t)(kt) * 64 + (kh) * 32;             \
    char* _dp = smem + 65536 + (bufx) * 32768 + (kh) * 16384 + w * 1024;       \
    GLL16(_s, _dp); GLL16(_s + 128 * KD, _dp + 8192); }

#define LOADB(bufx, ks) {                                                      \
    const char* _bb = smem + 65536 + (bufx) * 32768 + (ks) * 16384 + bR0;      \
    bk[ks][0] = *(const bf16x8*)(_bb);                                         \
    bk[ks][1] = *(const bf16x8*)(_bb + 1024);                                  \
    bk[ks][2] = *(const bf16x8*)(_bb + 2048);                                  \
    bk[ks][3] = *(const bf16x8*)(_bb + 3072); }

#define PHASE(bufx, mh, ks, LOADB_STMT, STAGE_STMT, VM_STMT) {                 \
    bf16x8 af[4];                                                              \
    const char* _ab = smem + (bufx) * 32768 + (ks) * 16384 + aR0 + (mh) * 4096;\
    af[0] = *(const bf16x8*)(_ab);                                             \
    af[1] = *(const bf16x8*)(_ab + 1024);                                      \
    af[2] = *(const bf16x8*)(_ab + 2048);                                      \
    af[3] = *(const bf16x8*)(_ab + 3072);                                      \
    LOADB_STMT;                                                                \
    STAGE_STMT;                                                                \
    VM_STMT;                                                                   \
    __builtin_amdgcn_s_barrier();                                              \
    asm volatile("s_waitcnt lgkmcnt(0)" ::: "memory");                         \
    __builtin_amdgcn_s_setprio(1);                                             \
    _Pragma("unroll") for (int _i = 0; _i < 4; ++_i)                           \
      _Pragma("unroll") for (int _n = 0; _n < 4; ++_n)                         \
        acc[(mh)*4+_i][_n] = __builtin_amdgcn_mfma_f32_16x16x32_bf16(          \
            af[_i], bk[ks][_n], acc[(mh)*4+_i][_n], 0, 0, 0);                  \
    __builtin_amdgcn_s_setprio(0);                                             \
    __builtin_amdgcn_s_barrier(); }

__global__ __launch_bounds__(512, 2) void gemm256_kernel(
    const unsigned short* __restrict__ A,   // [32768][1024] bf16
    const unsigned short* __restrict__ B,   // [1024][1024] bf16 (W row-major = B^T)
    float* __restrict__ C)                  // [32768][1024] f32
{
    __shared__ char smem[131072];

    const int t = threadIdx.x;
    const int w = t >> 6, l = t & 63;
    const int wm = w >> 2, wn = w & 3;

    // XCD-aware swizzle (nwg = 512, divisible by 8)
    const int bid = blockIdx.x;
    const int swz = (bid & 7) * 64 + (bid >> 3);
    const int tile_m = swz >> 2, tile_n = swz & 3;

    // staging source (per-lane, pre-swizzled 16B granule)
    const int r0 = w * 16 + (l >> 2);
    const int gsrc = (l & 3) ^ ((l >> 3) & 3);
    const unsigned short* aG = A + (size_t)(tile_m * 256 + r0) * KD + gsrc * 8;
    const unsigned short* bG = B + (size_t)(tile_n * 256 + r0) * KD + gsrc * 8;

    // reader bases (byte offsets into smem)
    const int gq = (l >> 4) ^ ((l >> 1) & 3);
    const int aR0 = (wm * 128 + (l & 15)) * 64 + gq * 16;
    const int bR0 = (wn * 64 + (l & 15)) * 64 + gq * 16;

    f32x4 acc[8][4] = {};
    bf16x8 bk[2][4];

    // ---- prologue (tile 0): issue [Ak0, Bk0, Bk1, Ak1]; leave [Bk1, Ak1] in flight ----
    ASTAGE(0, 0, 0);                     // A-kh0  (2 GLL)
    BSTAGE(0, 0, 0);                     // B-kh0  (2 GLL)
    BSTAGE(0, 1, 0);                     // B-kh1  (2 GLL)
    ASTAGE(0, 1, 0);                     // A-kh1  (2 GLL)
    VMW(4);                              // Ak0, Bk0 landed; [Bk1, Ak1] in flight
    __builtin_amdgcn_s_barrier();

    // ---- main loop; invariant entering q0: O = [Bk1(tt), Ak1(tt)] ----
    for (int tt = 0; tt < 16; ++tt) {
        const int bc = tt & 1;             // buffer index 0/1 (macros scale)
        const int bn = bc ^ 1;
        const int T1 = (tt + 1) & 15;      // prefetch K-tile index (wraps; tail harmless)

        // q0 (mh0,ks0): stage A-kh0'; VMW(2) retires Bk1(tt),Ak1(tt) for q1
        PHASE(bc, 0, 0, LOADB(bc, 0), ASTAGE(bn, 0, T1), VMW(2));
        // q1 (mh0,ks1): stage B-kh0' + B-kh1'
        PHASE(bc, 0, 1, LOADB(bc, 1), { BSTAGE(bn, 0, T1); BSTAGE(bn, 1, T1); }, );
        // q2 (mh1,ks0): stage A-kh1'
        PHASE(bc, 1, 0,             , ASTAGE(bn, 1, T1), );
        // q3 (mh1,ks1): VMW(4) retires Ak0',Bk0' for next q0
        PHASE(bc, 1, 1,             ,                  , VMW(4));
    }
    VMW(0);   // retire wrapped tile-16 stages

    // ---- epilogue: C/D layout col=lane&15, row=(lane>>4)*4+reg ----
    float* Cp = C + (size_t)(tile_m * 256 + wm * 128 + ((l >> 4) * 4)) * ND
                  + tile_n * 256 + wn * 64 + (l & 15);
    #pragma unroll
    for (int m = 0; m < 8; ++m)
        #pragma unroll
        for (int n = 0; n < 4; ++n)
            #pragma unroll
            for (int j = 0; j < 4; ++j)
                Cp[(size_t)(m * 16 + j) * ND + n * 16] = acc[m][n][j];
}

extern "C" void kernel_launch(void* const* d_in, const int* in_sizes, int n_in,
                              void* d_out, int out_size, void* d_ws, size_t ws_size,
                              hipStream_t stream) {
    const float* x  = (const float*)d_in[0];   // [4,8192,1024] fp32
    const float* wt = (const float*)d_in[1];   // [1024,1024] fp32
    float* out = (float*)d_out;                // [4,8192,1024] fp32

    unsigned short* Abf = (unsigned short*)d_ws;                    // 64 MiB
    unsigned short* Wbf = Abf + (size_t)32768 * 1024;               // +2 MiB

    prune_scale_kernel<<<33792, 256, 0, stream>>>(x, Abf, wt, Wbf);
    gemm256_kernel<<<512, 512, 0, stream>>>(Abf, Wbf, out);
}